// Round 3
// baseline (374.672 us; speedup 1.0000x reference)
//
#include <hip/hip_runtime.h>
#include <math.h>

// YOLOv5 head, 3-kernel pipeline:
//  1) convert_w_all: weights -> frag-contiguous bf16 in ws (as round 2).
//  2) convert_p_all: activations fp32 [C][HW] -> frag-contiguous bf16 A-tiles in ws
//     (64hw x 32k chunk = 4KB in exact MFMA lane order).
//  3) yolo_gemm (fused, all scales): barrier-free, LDS-free GEMM — per 32-K step each
//     wave does 8 coalesced dwordx4 loads + 16 MFMAs, 2-deep register double buffer.
// Fallback: if ws_size too small, use the verified round-2 single-kernel path.

#define NOUT 85
#define TOTAL_ROWS 25200

// workspace layout (ushort units)
#define WOFF0 0
#define WOFF1 65536
#define WOFF2 196608
#define PFRAG_OFF 458752                     // bytes 917504
#define PSZ0 26214400                        // 16*100*8*2048
#define PSZ1 13107200                        // 16*25*16*2048
#define PSZ2 7340032                         // 16*7*32*2048
#define POFF0 (PFRAG_OFF)
#define POFF1 (PFRAG_OFF + PSZ0)
#define POFF2 (PFRAG_OFF + PSZ0 + PSZ1)
#define WS_NEED_FULL ((size_t)(PFRAG_OFF + PSZ0 + PSZ1 + PSZ2) * 2)   // 94,240,768 B

typedef __attribute__((ext_vector_type(8))) short short8;
typedef __attribute__((ext_vector_type(4))) float floatx4;

__device__ __forceinline__ unsigned short f2bf(float x) {
    union { float f; unsigned u; } v; v.f = x;
    unsigned r = v.u + 0x7fffu + ((v.u >> 16) & 1u);  // RNE
    return (unsigned short)(r >> 16);
}

// Frag-contiguous weights: tile t = kt*16 + ot at shorts [t*512,t*512+512);
// lane l holds o = ot*16 + (l&15), k-octet kt*32 + (l>>4)*8.
__global__ __launch_bounds__(256) void convert_w_all(
    const float* __restrict__ w0, const float* __restrict__ w1,
    const float* __restrict__ w2, unsigned short* __restrict__ dst)
{
    int i = blockIdx.x * 256 + threadIdx.x;   // 0 .. 458751
    const float* w; int C, idx;
    if (i < 65536)       { w = w0; C = 256;  idx = i; }
    else if (i < 196608) { w = w1; C = 512;  idx = i - 65536; }
    else                 { w = w2; C = 1024; idx = i - 196608; }
    int j  = idx & 7;
    int l  = (idx >> 3) & 63;
    int t  = idx >> 9;
    int ot = t & 15, kt = t >> 4;
    int o  = ot * 16 + (l & 15);
    int k  = kt * 32 + (l >> 4) * 8 + j;
    float v = (o < 255) ? w[(size_t)o * C + k] : 0.f;   // rows 255+ = zero pad
    dst[i] = f2bf(v);
}

// Frag-contiguous activations. Chunk c = ((b*T + t)*S + s) holds the 64hw x 32k
// A-tile for (batch b, hw-tile t, k-step s) as [ni][l][8]: lane l=(q*16+ml) of
// sub-tile ni holds p[s*32+q*8 .. +8][t*64+ni*16+ml] (hw clamped at HW-1).
// One thread per 16B output chunk; 8 strided fp32 reads (coalesced across ml),
// one contiguous uint4 store. dst chunk index == global thread index.
__global__ __launch_bounds__(256) void convert_p_all(
    const float* __restrict__ p0, const float* __restrict__ p1,
    const float* __restrict__ p2, unsigned short* __restrict__ ws)
{
    int i = blockIdx.x * 256 + threadIdx.x;   // 0 .. 5,832,703
    const float* p; int C, HW; int b, t, s, lc;
    if (i < 3276800) {                         // scale 0: 16b x 100t x 8s x 256
        p = p0; C = 256; HW = 6400;
        lc = i & 255; s = (i >> 8) & 7;  int bt = i >> 11;
        b = bt / 100; t = bt - b * 100;
    } else if (i < 4915200) {                  // scale 1: 16 x 25 x 16 x 256
        int idx = i - 3276800;
        p = p1; C = 512; HW = 1600;
        lc = idx & 255; s = (idx >> 8) & 15; int bt = idx >> 12;
        b = bt / 25;  t = bt - b * 25;
    } else {                                   // scale 2: 16 x 7 x 32 x 256
        int idx = i - 4915200;
        p = p2; C = 1024; HW = 400;
        lc = idx & 255; s = (idx >> 8) & 31; int bt = idx >> 13;
        b = bt / 7;   t = bt - b * 7;
    }
    int ni = lc >> 6, l = lc & 63, q = l >> 4, ml = l & 15;
    int hw = t * 64 + ni * 16 + ml; if (hw >= HW) hw = HW - 1;
    const float* src = p + ((size_t)b * C + (s * 32 + q * 8)) * HW + hw;
    unsigned d[4];
#pragma unroll
    for (int r = 0; r < 4; ++r) {
        float a  = src[(size_t)(2 * r) * HW];
        float bb = src[(size_t)(2 * r + 1) * HW];
        d[r] = (unsigned)f2bf(a) | ((unsigned)f2bf(bb) << 16);
    }
    ((uint4*)(ws + PFRAG_OFF))[(size_t)i] = make_uint4(d[0], d[1], d[2], d[3]);
}

// ---------------- barrier-free fused GEMM over pre-packed frags ----------------
__global__ __launch_bounds__(256) void yolo_gemm(
    const unsigned short* __restrict__ ws,
    const float* __restrict__ b0v, const float* __restrict__ b1v,
    const float* __restrict__ b2v, const float* __restrict__ anc,  // [3,3,2]
    float* __restrict__ out)
{
    const int tid = threadIdx.x;
    const int l   = tid & 63;
    const int wv  = tid >> 6;          // wave id: o-stripe [64*wv, 64*wv+64)
    const int ml  = l & 15;
    const int q   = l >> 4;

    const int x = blockIdx.x;          // scale2 blocks first (longest K)
    const float* bias; const float* an;
    int C, HW, row_off, sh, tile, b, T; size_t wOff, pOff; float stride_;
    if (x < 112) {                       // scale 2: 7 tiles x 16 b
        b = x / 7;  tile = x - b * 7;  T = 7;
        wOff = WOFF2; pOff = POFF2; bias = b2v; an = anc + 12;
        C = 1024; HW = 400; row_off = 24000; sh = 2; stride_ = 32.f;
    } else if (x < 512) {                // scale 1: 25 x 16
        int i = x - 112; b = i / 25; tile = i - b * 25; T = 25;
        wOff = WOFF1; pOff = POFF1; bias = b1v; an = anc + 6;
        C = 512; HW = 1600; row_off = 19200; sh = 3; stride_ = 16.f;
    } else {                             // scale 0: 100 x 16
        int i = x - 512; b = i / 100; tile = i - b * 100; T = 100;
        wOff = WOFF0; pOff = POFF0; bias = b0v; an = anc;
        C = 256; HW = 6400; row_off = 0; sh = 4; stride_ = 8.f;
    }
    const int hw0 = tile * 64;
    const int S   = C >> 5;              // 8 / 16 / 32 (even)

    const unsigned short* pfp = ws + pOff + (size_t)(b * T + tile) * S * 2048 + (l << 3);
    const unsigned short* wfp = ws + wOff + ((size_t)(wv * 4) << 9) + (l << 3);

    floatx4 acc[4][4];                   // [ni(hw)][mi(o)]
#pragma unroll
    for (int ni = 0; ni < 4; ++ni)
#pragma unroll
        for (int mi = 0; mi < 4; ++mi)
            acc[ni][mi] = floatx4{0.f, 0.f, 0.f, 0.f};

#define GLOADP(dst, s_) do { const unsigned short* _b = pfp + (size_t)(s_) * 2048;  \
        _Pragma("unroll") for (int _n = 0; _n < 4; ++_n)                            \
            dst[_n] = *(const short8*)(_b + (_n << 9)); } while (0)
#define GLOADW(dst, s_) do { const unsigned short* _b = wfp + (size_t)(s_) * 8192;  \
        _Pragma("unroll") for (int _m = 0; _m < 4; ++_m)                            \
            dst[_m] = *(const short8*)(_b + (_m << 9)); } while (0)
#define GMFMA(pf, wf) do { _Pragma("unroll") for (int _n = 0; _n < 4; ++_n)         \
        _Pragma("unroll") for (int _m = 0; _m < 4; ++_m)                            \
            acc[_n][_m] = __builtin_amdgcn_mfma_f32_16x16x32_bf16(                  \
                pf[_n], wf[_m], acc[_n][_m], 0, 0, 0); } while (0)

    short8 pfA[4], wfA[4], pfB[4], wfB[4];
    GLOADP(pfA, 0); GLOADW(wfA, 0);
    GLOADP(pfB, 1); GLOADW(wfB, 1);      // S >= 8 always

    int s = 0;
    for (; s + 2 < S; s += 2) {
        GMFMA(pfA, wfA);
        GLOADP(pfA, s + 2); GLOADW(wfA, s + 2);
        GMFMA(pfB, wfB);
        GLOADP(pfB, s + 3); GLOADW(wfB, s + 3);
    }
    GMFMA(pfA, wfA);
    GMFMA(pfB, wfB);
#undef GLOADP
#undef GLOADW
#undef GMFMA

    // ---- epilogue (verified round-2 path): D row = ni*16+q*4+r (hw), col = mi*16+ml (o)
    const int nx = 5 << sh;
#pragma unroll
    for (int mi = 0; mi < 4; ++mi) {
        const int  o     = wv * 64 + mi * 16 + ml;
        const bool valid = (o < 255);
        const int  osafe = valid ? o : 254;
        const int  a     = osafe / 85;
        const int  oo    = osafe - a * 85;
        const float bi   = bias[osafe];
        const float anw  = an[a * 2 + 0];
        const float anh  = an[a * 2 + 1];
        float* orow = out + ((size_t)b * TOTAL_ROWS + row_off + a * HW) * NOUT + oo;
#pragma unroll
        for (int ni = 0; ni < 4; ++ni) {
            const int hwb = hw0 + ni * 16 + q * 4;
            if (hwb >= HW) continue;     // uniform per 16-lane group (HW % 16 == 0)
#pragma unroll
            for (int r = 0; r < 4; ++r) {
                const int hw = hwb + r;
                float y = acc[ni][mi][r] + bi;
                float sg = 1.f / (1.f + __expf(-y));
                float v;
                if (oo >= 4) {
                    v = sg;
                } else {
                    unsigned gy = (unsigned)(((unsigned long long)(unsigned)(hw >> sh)
                                             * 0xCCCCCCCDull) >> 34);   // (hw>>sh)/5
                    int gx = hw - (int)gy * nx;
                    if (oo == 0)      v = (2.f * sg + (float)gx - 0.5f) * stride_;
                    else if (oo == 1) v = (2.f * sg + (float)gy - 0.5f) * stride_;
                    else { float tt = 2.f * sg; v = tt * tt * ((oo == 2) ? anw : anh); }
                }
                if (valid) orow[(size_t)hw * NOUT] = v;
            }
        }
    }
}

// ---------------- fallback: verified round-2 single-kernel path ----------------
__global__ __launch_bounds__(256) void yolo_fused(
    const float* __restrict__ p0, const float* __restrict__ p1,
    const float* __restrict__ p2, const unsigned short* __restrict__ wsA,
    const float* __restrict__ b0v, const float* __restrict__ b1v,
    const float* __restrict__ b2v, const float* __restrict__ anc,
    float* __restrict__ out)
{
    __shared__ __align__(16) unsigned short Bl0[64 * 32];
    __shared__ __align__(16) unsigned short Bl1[64 * 32];

    const int tid = threadIdx.x;
    const int l   = tid & 63;
    const int wv  = tid >> 6;
    const int ml  = l & 15;
    const int q   = l >> 4;

    const int x = blockIdx.x;
    const float* p; const unsigned short* wA; const float* bias; const float* an;
    int C, HW, row_off, sh, tile, b; float stride_;
    if (x < 112) {
        b = x / 7;  tile = x - b * 7;
        p = p2; wA = wsA + WOFF2; bias = b2v; an = anc + 12;
        C = 1024; HW = 400; row_off = 24000; sh = 2; stride_ = 32.f;
    } else if (x < 512) {
        int i = x - 112; b = i / 25; tile = i - b * 25;
        p = p1; wA = wsA + WOFF1; bias = b1v; an = anc + 6;
        C = 512; HW = 1600; row_off = 19200; sh = 3; stride_ = 16.f;
    } else {
        int i = x - 512; b = i / 100; tile = i - b * 100;
        p = p0; wA = wsA + WOFF0; bias = b0v; an = anc;
        C = 256; HW = 6400; row_off = 0; sh = 4; stride_ = 8.f;
    }
    const int hw0   = tile * 64;
    const int iters = C >> 5;

    floatx4 acc[4][4];
#pragma unroll
    for (int ni = 0; ni < 4; ++ni)
#pragma unroll
        for (int mi = 0; mi < 4; ++mi)
            acc[ni][mi] = floatx4{0.f, 0.f, 0.f, 0.f};

    const float* pb = p + (size_t)b * C * HW;
    int scol = hw0 + l; if (scol >= HW) scol = HW - 1;
    const float* pcol0 = pb + (size_t)(wv * 8) * HW + scol;
    const size_t kj = (size_t)32 * HW;

    const int wchunk = wv ^ (l & 3) ^ ((l >> 2) & 3);
    const unsigned short* wfb = wA + ((size_t)(wv * 4) << 9) + (l << 3);

    float  bvA[8], bvB[8];
    short8 wfA[4], wfB[4];

#define LOADBV(dst, s) do { const float* _pc = pcol0 + (size_t)(s) * kj;          \
        _Pragma("unroll") for (int _r = 0; _r < 8; ++_r)                          \
            dst[_r] = _pc[(size_t)_r * HW]; } while (0)
#define LOADWF(dst, s) do { const unsigned short* _wb = wfb + (size_t)(s) * 8192; \
        _Pragma("unroll") for (int _m = 0; _m < 4; ++_m)                          \
            dst[_m] = *(const short8*)(_wb + (_m << 9)); } while (0)
#define PACK(src, BUF) do {                                                       \
        unsigned _p0 = (unsigned)f2bf(src[0]) | ((unsigned)f2bf(src[1]) << 16);   \
        unsigned _p1 = (unsigned)f2bf(src[2]) | ((unsigned)f2bf(src[3]) << 16);   \
        unsigned _p2 = (unsigned)f2bf(src[4]) | ((unsigned)f2bf(src[5]) << 16);   \
        unsigned _p3 = (unsigned)f2bf(src[6]) | ((unsigned)f2bf(src[7]) << 16);   \
        ((uint4*)BUF)[l * 4 + wchunk] = make_uint4(_p0, _p1, _p2, _p3); } while (0)
#define READPF(pf, BUF) do { _Pragma("unroll") for (int _n = 0; _n < 4; ++_n) {   \
        int _nn = _n * 16 + ml; int _ck = q ^ (_nn & 3) ^ ((_nn >> 2) & 3);       \
        pf[_n] = *(const short8*)(BUF + _nn * 32 + _ck * 8); } } while (0)
#define MFMA16(pf, wf) do { _Pragma("unroll") for (int _n = 0; _n < 4; ++_n)      \
        _Pragma("unroll") for (int _m = 0; _m < 4; ++_m)                          \
            acc[_n][_m] = __builtin_amdgcn_mfma_f32_16x16x32_bf16(                \
                pf[_n], wf[_m], acc[_n][_m], 0, 0, 0); } while (0)
#define LGKM_BARRIER() do { asm volatile("s_waitcnt lgkmcnt(0)" ::: "memory");    \
        __builtin_amdgcn_s_barrier(); asm volatile("" ::: "memory"); } while (0)

    LOADBV(bvA, 0);
    LOADBV(bvB, 1);
    LOADWF(wfA, 0);
    PACK(bvA, Bl0);
    LOADBV(bvA, 2);
    LGKM_BARRIER();

    for (int it = 0; it < iters; it += 2) {
        short8 pfA[4];
        READPF(pfA, Bl0);
        PACK(bvB, Bl1);
        if (it + 3 < iters) LOADBV(bvB, it + 3);
        LOADWF(wfB, it + 1);
        LGKM_BARRIER();
        MFMA16(pfA, wfA);

        short8 pfB[4];
        READPF(pfB, Bl1);
        if (it + 2 < iters) {
            PACK(bvA, Bl0);
            if (it + 4 < iters) LOADBV(bvA, it + 4);
            LOADWF(wfA, it + 2);
            LGKM_BARRIER();
        }
        MFMA16(pfB, wfB);
    }

    const int nx = 5 << sh;
#pragma unroll
    for (int mi = 0; mi < 4; ++mi) {
        const int  o     = wv * 64 + mi * 16 + ml;
        const bool valid = (o < 255);
        const int  osafe = valid ? o : 254;
        const int  a     = osafe / 85;
        const int  oo    = osafe - a * 85;
        const float bi   = bias[osafe];
        const float anw  = an[a * 2 + 0];
        const float anh  = an[a * 2 + 1];
        float* orow = out + ((size_t)b * TOTAL_ROWS + row_off + a * HW) * NOUT + oo;
#pragma unroll
        for (int ni = 0; ni < 4; ++ni) {
            const int hwb = hw0 + ni * 16 + q * 4;
            if (hwb >= HW) continue;
#pragma unroll
            for (int r = 0; r < 4; ++r) {
                const int hw = hwb + r;
                float y = acc[ni][mi][r] + bi;
                float sg = 1.f / (1.f + __expf(-y));
                float v;
                if (oo >= 4) {
                    v = sg;
                } else {
                    unsigned gy = (unsigned)(((unsigned long long)(unsigned)(hw >> sh)
                                             * 0xCCCCCCCDull) >> 34);
                    int gx = hw - (int)gy * nx;
                    if (oo == 0)      v = (2.f * sg + (float)gx - 0.5f) * stride_;
                    else if (oo == 1) v = (2.f * sg + (float)gy - 0.5f) * stride_;
                    else { float tt = 2.f * sg; v = tt * tt * ((oo == 2) ? anw : anh); }
                }
                if (valid) orow[(size_t)hw * NOUT] = v;
            }
        }
    }
#undef LOADBV
#undef LOADWF
#undef PACK
#undef READPF
#undef MFMA16
#undef LGKM_BARRIER
}

extern "C" void kernel_launch(void* const* d_in, const int* in_sizes, int n_in,
                              void* d_out, int out_size, void* d_ws, size_t ws_size,
                              hipStream_t stream) {
    const float* p0 = (const float*)d_in[0];
    const float* p1 = (const float*)d_in[1];
    const float* p2 = (const float*)d_in[2];
    const float* w0 = (const float*)d_in[3];
    const float* b0 = (const float*)d_in[4];
    const float* w1 = (const float*)d_in[5];
    const float* b1 = (const float*)d_in[6];
    const float* w2 = (const float*)d_in[7];
    const float* b2 = (const float*)d_in[8];
    const float* anc = (const float*)d_in[9];  // [3,3,2]
    float* out = (float*)d_out;

    unsigned short* wsA = (unsigned short*)d_ws;

    convert_w_all<<<dim3(458752 / 256), dim3(256), 0, stream>>>(w0, w1, w2, wsA);

    if (ws_size >= WS_NEED_FULL) {
        // 5,832,704 chunks / 256 = 22784 blocks
        convert_p_all<<<dim3(22784), dim3(256), 0, stream>>>(p0, p1, p2, wsA);
        yolo_gemm<<<dim3(2112), dim3(256), 0, stream>>>(
            wsA, b0, b1, b2, anc, out);
    } else {
        yolo_fused<<<dim3(2112), dim3(256), 0, stream>>>(
            p0, p1, p2, wsA, b0, b1, b2, anc, out);
    }
}

// Round 4
// 330.661 us; speedup vs baseline: 1.1331x; 1.1331x over previous
//
#include <hip/hip_runtime.h>
#include <math.h>

// YOLOv5 head, fused single-kernel bf16 MFMA GEMM for all 3 scales.
//   D[hw][o] = sum_c p[b,c,hw] * w[o,c]   (p-frag = MFMA A, w-frag = MFMA B)
// Per block (64 hw x 256 o):
//   1) stage ENTIRE K-chunk (<=512 c) of activations fp32->bf16 into LDS in MFMA
//      frag layout (fully-coalesced 256B row reads, XOR-swizzled 16B slots)
//   2) ONE barrier, then barrier-free MFMA sweep; weights from L2-hot
//      frag-contiguous ws (1KB coalesced loads, register double-buffered)
//   3) decode epilogue into 64KB LDS out-tile, barrier, contiguous dword flush
//      (per anchor: 21,760 contiguous bytes -> no partial-line write waste)
// Weights pre-packed frag-contiguous by convert_w_all (verified round 2/3).

#define NOUT 85
#define TOTAL_ROWS 25200

// ws layout (ushort units)
#define WOFF0 0
#define WOFF1 65536
#define WOFF2 196608

typedef __attribute__((ext_vector_type(8))) short short8;
typedef __attribute__((ext_vector_type(4))) float floatx4;

__device__ __forceinline__ unsigned short f2bf(float x) {
    union { float f; unsigned u; } v; v.f = x;
    unsigned r = v.u + 0x7fffu + ((v.u >> 16) & 1u);  // RNE
    return (unsigned short)(r >> 16);
}

// Frag-contiguous weights: tile t = kt*16 + ot at shorts [t*512,t*512+512);
// lane l holds o = ot*16 + (l&15), k-octet kt*32 + (l>>4)*8.
__global__ __launch_bounds__(256) void convert_w_all(
    const float* __restrict__ w0, const float* __restrict__ w1,
    const float* __restrict__ w2, unsigned short* __restrict__ dst)
{
    int i = blockIdx.x * 256 + threadIdx.x;   // 0 .. 458751
    const float* w; int C, idx;
    if (i < 65536)       { w = w0; C = 256;  idx = i; }
    else if (i < 196608) { w = w1; C = 512;  idx = i - 65536; }
    else                 { w = w2; C = 1024; idx = i - 196608; }
    int j  = idx & 7;
    int l  = (idx >> 3) & 63;
    int t  = idx >> 9;
    int ot = t & 15, kt = t >> 4;
    int o  = ot * 16 + (l & 15);
    int k  = kt * 32 + (l >> 4) * 8 + j;
    float v = (o < 255) ? w[(size_t)o * C + k] : 0.f;   // rows 255+ = zero pad
    dst[i] = f2bf(v);
}

__global__ __launch_bounds__(256) void yolo_fused2(
    const float* __restrict__ p0, const float* __restrict__ p1,
    const float* __restrict__ p2, const unsigned short* __restrict__ wsA,
    const float* __restrict__ b0v, const float* __restrict__ b1v,
    const float* __restrict__ b2v, const float* __restrict__ anc,  // [3,3,2]
    float* __restrict__ out)
{
    __shared__ __align__(16) unsigned char smem[65536];   // union: act tile / out tile
    unsigned short* act = (unsigned short*)smem;
    float*          ob  = (float*)smem;

    const int tid = threadIdx.x;
    const int l   = tid & 63;
    const int wv  = tid >> 6;          // wave id: o-stripe [64*wv, 64*wv+64)
    const int ml  = l & 15;
    const int q   = l >> 4;

    // scale select: scale2 blocks first (longest K -> start earliest)
    const int x = blockIdx.x;
    const float* p; const unsigned short* wA; const float* bias; const float* an;
    int C, HW, row_off, sh, tile, b; float stride_;
    if (x < 112) {                       // scale 2: 7 tiles x 16 b
        b = x / 7;  tile = x - b * 7;
        p = p2; wA = wsA + WOFF2; bias = b2v; an = anc + 12;
        C = 1024; HW = 400; row_off = 24000; sh = 2; stride_ = 32.f;
    } else if (x < 512) {                // scale 1: 25 x 16
        int i = x - 112; b = i / 25; tile = i - b * 25;
        p = p1; wA = wsA + WOFF1; bias = b1v; an = anc + 6;
        C = 512; HW = 1600; row_off = 19200; sh = 3; stride_ = 16.f;
    } else {                             // scale 0: 100 x 16
        int i = x - 512; b = i / 100; tile = i - b * 100;
        p = p0; wA = wsA + WOFF0; bias = b0v; an = anc;
        C = 256; HW = 6400; row_off = 0; sh = 4; stride_ = 8.f;
    }
    const int hw0 = tile * 64;
    const int S   = C >> 5;              // 8 / 16 / 32 total 32-k steps
    const int Sc  = (S < 16) ? S : 16;   // steps per LDS chunk (<=64KB)
    const int nch = (S > 16) ? (S >> 4) : 1;

    floatx4 acc[4][4];                   // [ni(hw)][mi(o)]
#pragma unroll
    for (int ni = 0; ni < 4; ++ni)
#pragma unroll
        for (int mi = 0; mi < 4; ++mi)
            acc[ni][mi] = floatx4{0.f, 0.f, 0.f, 0.f};

    // staging task decomposition: thread = (s_loc, c-octet, hw-quad)
    const int s_loc = tid >> 6;          // 0..3 (4 k-steps staged per round)
    const int co    = (tid >> 4) & 3;    // c-octet within k-step
    const int hq    = tid & 15;          // hw-quad
    int hwq = hw0 + hq * 4;
    if (hwq + 4 > HW) hwq = HW - 4;      // clamp (scale2 tail), dup data unused
    const float* pb = p + (size_t)b * C * HW;

    // w-frag base: wave's ot range [wv*4, wv*4+4); per-k-step stride = 8192 shorts
    const unsigned short* wfp = wA + ((size_t)(wv * 4) << 9) + (l << 3);

#define LOADWF(dst, s_) do { const unsigned short* _b = wfp + (size_t)(s_) * 8192;  \
        _Pragma("unroll") for (int _m = 0; _m < 4; ++_m)                            \
            dst[_m] = *(const short8*)(_b + (_m << 9)); } while (0)
#define READPF(pf, s_) do { _Pragma("unroll") for (int _n = 0; _n < 4; ++_n) {      \
        int _a16 = (((s_) * 4 + _n) << 6) + l; _a16 ^= (_a16 >> 4) & 7;             \
        pf[_n] = *(const short8*)(act + (_a16 << 3)); } } while (0)
#define GMFMA(pf, wf) do { _Pragma("unroll") for (int _n = 0; _n < 4; ++_n)         \
        _Pragma("unroll") for (int _m = 0; _m < 4; ++_m)                            \
            acc[_n][_m] = __builtin_amdgcn_mfma_f32_16x16x32_bf16(                  \
                pf[_n], wf[_m], acc[_n][_m], 0, 0, 0); } while (0)

    for (int ch = 0; ch < nch; ++ch) {
        if (ch) __syncthreads();         // prev chunk's frag reads done
        const int cb = ch * Sc * 32;

        // ---- stage chunk: Sc/4 rounds, 8 coalesced float4 row-reads per round ----
        for (int r = 0; r < (Sc >> 2); ++r) {
            const int s = r * 4 + s_loc;
            const int c = cb + s * 32 + co * 8;
            floatx4 v[8];
#pragma unroll
            for (int i = 0; i < 8; ++i)
                v[i] = *(const floatx4*)(pb + (size_t)(c + i) * HW + hwq);
#pragma unroll
            for (int e = 0; e < 4; ++e) {
                const int hwr = hq * 4 + e;
                const int ni = hwr >> 4, mll = hwr & 15;
                unsigned d0 = (unsigned)f2bf(v[0][e]) | ((unsigned)f2bf(v[1][e]) << 16);
                unsigned d1 = (unsigned)f2bf(v[2][e]) | ((unsigned)f2bf(v[3][e]) << 16);
                unsigned d2 = (unsigned)f2bf(v[4][e]) | ((unsigned)f2bf(v[5][e]) << 16);
                unsigned d3 = (unsigned)f2bf(v[6][e]) | ((unsigned)f2bf(v[7][e]) << 16);
                int a16 = ((s * 4 + ni) << 6) + co * 16 + mll;
                a16 ^= (a16 >> 4) & 7;   // bank-group spread (same XOR on read)
                *(uint4*)(act + (a16 << 3)) = make_uint4(d0, d1, d2, d3);
            }
        }
        __syncthreads();                 // the ONLY barrier in the K path

        // ---- compute chunk: barrier-free MFMA sweep ----
        const int gs0 = ch * Sc;
        short8 wfA[4], wfB[4];
        LOADWF(wfA, gs0);
        LOADWF(wfB, gs0 + 1);
        for (int s = 0; s < Sc; s += 2) {
            short8 pfA[4], pfB[4];
            READPF(pfA, s);
            GMFMA(pfA, wfA);
            if (s + 2 < Sc) LOADWF(wfA, gs0 + s + 2);
            READPF(pfB, s + 1);
            GMFMA(pfB, wfB);
            if (s + 3 < Sc) LOADWF(wfB, gs0 + s + 3);
        }
    }
#undef LOADWF
#undef READPF
#undef GMFMA

    // ---- decode epilogue into LDS out-tile [a][hw_rel][oo] (a-stride 5440) ----
    __syncthreads();                     // all frag reads done before overwrite
    const int nx = 5 << sh;
#pragma unroll
    for (int mi = 0; mi < 4; ++mi) {
        const int  o     = wv * 64 + mi * 16 + ml;
        const bool valid = (o < 255);
        const int  osafe = valid ? o : 254;
        const int  a     = osafe / 85;
        const int  oo    = osafe - a * 85;
        const float bi   = bias[osafe];
        const float anw  = an[a * 2 + 0];
        const float anh  = an[a * 2 + 1];
        const int  lbase = a * 5440 + oo;
#pragma unroll
        for (int ni = 0; ni < 4; ++ni) {
            const int hwr0 = ni * 16 + q * 4;
            if (hw0 + hwr0 >= HW) continue;   // uniform per 16-lane group
#pragma unroll
            for (int rr = 0; rr < 4; ++rr) {
                const int hwr = hwr0 + rr;
                const int hw  = hw0 + hwr;
                float y  = acc[ni][mi][rr] + bi;
                float sg = 1.f / (1.f + __expf(-y));
                float v;
                if (oo >= 4) {
                    v = sg;
                } else {
                    unsigned gy = (unsigned)(((unsigned long long)(unsigned)(hw >> sh)
                                             * 0xCCCCCCCDull) >> 34);   // (hw>>sh)/5
                    int gx = hw - (int)gy * nx;
                    if (oo == 0)      v = (2.f * sg + (float)gx - 0.5f) * stride_;
                    else if (oo == 1) v = (2.f * sg + (float)gy - 0.5f) * stride_;
                    else { float tt = 2.f * sg; v = tt * tt * ((oo == 2) ? anw : anh); }
                }
                if (valid) ob[lbase + hwr * 85] = v;
            }
        }
    }
    __syncthreads();

    // ---- contiguous flush: 3 anchors x ne*85 floats, fully-coalesced dwords ----
    const int ne   = (HW - hw0 < 64) ? (HW - hw0) : 64;
    const int ne85 = ne * 85;
    float* gb = out + ((size_t)b * TOTAL_ROWS + row_off + hw0) * NOUT;
    const size_t astr = (size_t)HW * NOUT;
    const int ftot = 3 * ne85;
    for (int f = tid; f < ftot; f += 256) {
        int a  = (f >= ne85) + (f >= 2 * ne85);
        int k2 = f - a * ne85;
        gb[(size_t)a * astr + k2] = ob[a * 5440 + k2];
    }
}

extern "C" void kernel_launch(void* const* d_in, const int* in_sizes, int n_in,
                              void* d_out, int out_size, void* d_ws, size_t ws_size,
                              hipStream_t stream) {
    const float* p0 = (const float*)d_in[0];
    const float* p1 = (const float*)d_in[1];
    const float* p2 = (const float*)d_in[2];
    const float* w0 = (const float*)d_in[3];
    const float* b0 = (const float*)d_in[4];
    const float* w1 = (const float*)d_in[5];
    const float* b1 = (const float*)d_in[6];
    const float* w2 = (const float*)d_in[7];
    const float* b2 = (const float*)d_in[8];
    const float* anc = (const float*)d_in[9];  // [3,3,2]
    float* out = (float*)d_out;

    unsigned short* wsA = (unsigned short*)d_ws;   // needs 917504 B

    convert_w_all<<<dim3(458752 / 256), dim3(256), 0, stream>>>(w0, w1, w2, wsA);

    // fused: 112 scale2 blocks + 400 scale1 + 1600 scale0 = 2112
    yolo_fused2<<<dim3(2112), dim3(256), 0, stream>>>(
        p0, p1, p2, wsA, b0, b1, b2, anc, out);
}